// Round 4
// baseline (171.290 us; speedup 1.0000x reference)
//
#include <hip/hip_runtime.h>

// STFT: x[16, 262144] fp32, Hann 2048, hop 512, reflect pad 1024.
// Output: real[16,1025,513] ++ imag[16,1025,513], fp32.
//
// Round 11: two-tile software pipeline per block. R10 falsified the barrier-
// lockstep theory (barriers removed, still no overlap: convoy effect keeps
// waves phase-converged). R9/R10 both show dur ~= SUM of per-pipe times
// (VALU 17us + HBM 17us + LDS 9us ~= 49us measured), so the serializer is
// the per-block phase sequence: load -> fft -> store with nothing to overlap.
// This round merges the two block generations into one block:
//  - 1024 main blocks, each runs tile A=(b,g) then tile B=(b+8,g) [same g =>
//    same window/reflect indices per thread].
//  - After tile A's load barrier, tile B's 16 global loads per thread are
//    issued into registers (pa/pb, + w_p saved from A's loader: +24 VGPR,
//    base 24 -> ~50, fits the 64-VGPR / 8-waves-per-SIMD budget). Their HBM
//    latency hides under A's whole FFT+epilogue (~20us of cover).
//  - Tile A's scattered stores drain while tile B's FFT runs.
//  - FFT core + loader + epilogue are exactly R9's proven versions
//    (coalesced loads, 5 barriers/tile, octet-swizzle write merging).
//  - Tail blocks (frame 512 per batch) are ids 0..15 so they run FIRST and
//    don't straggle at kernel end. Grid 1040 = 16 tail + 1024 main.

#define N_FFT   2048
#define LOG2N   11
#define HOP     512
#define PADL    1024
#define NBINS   1025
#define NFRAMES 513
#define NBATCH  16
#define TLEN    262144

#define HALF_OUT ((size_t)NBATCH * NBINS * NFRAMES)   // 8,413,200 floats per plane

__device__ __forceinline__ int pidx(int a) { return a + (a >> 5); }

__device__ __forceinline__ int refl(int j) {
    if (j < 0)          j = -j;
    else if (j >= TLEN) j = 2 * TLEN - 2 - j;
    return j;
}

__device__ __forceinline__ int brev11(int n) {
    return (int)(__brev((unsigned)n) >> 21);
}

__device__ __forceinline__ float2 cmul(float2 a, float2 w) {
    return make_float2(fmaf(a.x, w.x, -a.y * w.y), fmaf(a.x, w.y, a.y * w.x));
}
__device__ __forceinline__ float2 cadd(float2 a, float2 b) {
    return make_float2(a.x + b.x, a.y + b.y);
}
__device__ __forceinline__ float2 csub(float2 a, float2 b) {
    return make_float2(a.x - b.x, a.y - b.y);
}
__device__ __forceinline__ float2 csqr(float2 w) {
    return make_float2(fmaf(w.x, w.x, -w.y * w.y), 2.0f * w.x * w.y);
}

// Three DIT stages (halves H, 2H, 4H) on points base + m*H, m=0..7, in registers.
template <int H, int L2H>
__device__ __forceinline__ void octet_pass(float2* __restrict__ zc, int q) {
    const int p    = q & (H - 1);
    const int base = ((q >> L2H) << (L2H + 3)) + p;
    int ia[8];
#pragma unroll
    for (int m = 0; m < 8; ++m) ia[m] = pidx(base + m * H);
    float2 v0 = zc[ia[0]], v1 = zc[ia[1]], v2 = zc[ia[2]], v3 = zc[ia[3]];
    float2 v4 = zc[ia[4]], v5 = zc[ia[5]], v6 = zc[ia[6]], v7 = zc[ia[7]];

    float2 w1, w2, w3;
    if (H == 1) {
        w3 = make_float2(1.0f, 0.0f); w2 = w3; w1 = w3;   // p==0 always
    } else {
        float s, c;
        __sincosf((float)p * (-3.14159265358979323846f / (4.0f * (float)H)), &s, &c);
        w3 = make_float2(c, s);
        w2 = csqr(w3);
        w1 = csqr(w2);
    }

    float2 t;
    // stage A (half=H): pairs (0,1)(2,3)(4,5)(6,7), all twiddle w1
    t = cmul(v1, w1); v1 = csub(v0, t); v0 = cadd(v0, t);
    t = cmul(v3, w1); v3 = csub(v2, t); v2 = cadd(v2, t);
    t = cmul(v5, w1); v5 = csub(v4, t); v4 = cadd(v4, t);
    t = cmul(v7, w1); v7 = csub(v6, t); v6 = cadd(v6, t);
    // stage B (half=2H): pairs (0,2)(4,6) w2 ; (1,3)(5,7) -i*w2
    const float2 w2m = make_float2(w2.y, -w2.x);
    t = cmul(v2, w2);  v2 = csub(v0, t); v0 = cadd(v0, t);
    t = cmul(v3, w2m); v3 = csub(v1, t); v1 = cadd(v1, t);
    t = cmul(v6, w2);  v6 = csub(v4, t); v4 = cadd(v4, t);
    t = cmul(v7, w2m); v7 = csub(v5, t); v5 = cadd(v5, t);
    // stage C (half=4H): pairs (0,4) w3 ; (1,5) w3*e^{-i pi/4} ; (2,6) -i*w3 ; (3,7) -i*w3*e^{-i pi/4}
    const float R = 0.70710678118654752f;
    const float2 w3o  = make_float2((w3.x + w3.y) * R, (w3.y - w3.x) * R);
    const float2 w3m  = make_float2(w3.y, -w3.x);
    const float2 w3mo = make_float2(w3o.y, -w3o.x);
    t = cmul(v4, w3);   v4 = csub(v0, t); v0 = cadd(v0, t);
    t = cmul(v5, w3o);  v5 = csub(v1, t); v1 = cadd(v1, t);
    t = cmul(v6, w3m);  v6 = csub(v2, t); v2 = cadd(v2, t);
    t = cmul(v7, w3mo); v7 = csub(v3, t); v3 = cadd(v3, t);

    zc[ia[0]] = v0; zc[ia[1]] = v1; zc[ia[2]] = v2; zc[ia[3]] = v3;
    zc[ia[4]] = v4; zc[ia[5]] = v5; zc[ia[6]] = v6; zc[ia[7]] = v7;
}

// Radix-4 quad item (stages 10-11, h=512) on plane zc, position p in [0,512).
__device__ __forceinline__ void quad_item(float2* __restrict__ zc, int p) {
    float s, cc;
    __sincosf((float)p * (-3.14159265358979323846f / 1024.0f), &s, &cc);
    const float2 w2  = make_float2(cc, s);        // exp(-i*pi*p/1024)
    const float2 w1  = csqr(w2);                  // exp(-i*pi*p/512)
    const float2 w2m = make_float2(w2.y, -w2.x);  // -i*w2
    const int i0 = pidx(p), i1 = pidx(p + 512), i2 = pidx(p + 1024), i3 = pidx(p + 1536);
    float2 v0 = zc[i0], v1 = zc[i1], v2 = zc[i2], v3 = zc[i3];
    float2 t;
    t = cmul(v1, w1); v1 = csub(v0, t); v0 = cadd(v0, t);
    t = cmul(v3, w1); v3 = csub(v2, t); v2 = cadd(v2, t);
    t = cmul(v2, w2);  v2 = csub(v0, t); v0 = cadd(v0, t);
    t = cmul(v3, w2m); v3 = csub(v1, t); v1 = cadd(v1, t);
    zc[i0] = v0; zc[i1] = v1; zc[i2] = v2; zc[i3] = v3;
}

// Full FFT on both planes (call with loader data in z, after a barrier).
// 4 internal barriers; leaves results in z, barrier at end included.
__device__ __forceinline__ void fft_main(float2 (*__restrict__ z)[2113], int tid) {
    const int c = tid >> 8, q = tid & 255;
    octet_pass<1, 0>(z[c], q);  __syncthreads();
    octet_pass<8, 3>(z[c], q);  __syncthreads();
    octet_pass<64, 6>(z[c], q); __syncthreads();
    quad_item(z[0], tid & 511);
    quad_item(z[1], tid & 511);
    __syncthreads();
}

// Conjugate-symmetry unpack + direct write of 4 frames (f0..f0+3) of batch b.
__device__ __forceinline__ void epi_main(const float2 (*__restrict__ z)[2113],
                                         float* __restrict__ outr,
                                         float* __restrict__ outi,
                                         int b, int f0, int tid) {
#pragma unroll
    for (int it = 0; it < 3; ++it) {
        const int k = tid + it * 512;
        if (k < NBINS) {
            const int km = (N_FFT - k) & (N_FFT - 1);
            const float2 zk0 = z[0][pidx(k)];
            const float2 zr0 = z[0][pidx(km)];
            const float2 zk1 = z[1][pidx(k)];
            const float2 zr1 = z[1][pidx(km)];
            const size_t o = ((size_t)b * NBINS + (size_t)k) * NFRAMES + (size_t)f0;
            outr[o + 0] = 0.5f * (zk0.x + zr0.x);   // even frame re
            outr[o + 1] = 0.5f * (zk0.y + zr0.y);   // odd frame re
            outr[o + 2] = 0.5f * (zk1.x + zr1.x);
            outr[o + 3] = 0.5f * (zk1.y + zr1.y);
            outi[o + 0] = 0.5f * (zk0.y - zr0.y);   // even frame im
            outi[o + 1] = 0.5f * (zr0.x - zk0.x);   // odd frame im
            outi[o + 2] = 0.5f * (zk1.y - zr1.y);
            outi[o + 3] = 0.5f * (zr1.x - zk1.x);
        }
    }
}

__global__ __launch_bounds__(512, 8) void stft_one(
    const float* __restrict__ x,
    const float* __restrict__ window,
    float* __restrict__ out)
{
    __shared__ float2 z[2][2113];     // 33,808 B -> 4 blocks/CU

    const int d   = blockIdx.x;
    const int tid = threadIdx.x;
    float* __restrict__ outr = out;
    float* __restrict__ outi = out + HALF_OUT;

    // ---------------- tail blocks: frame 512 of batch d, run first ----------
    if (d < NBATCH) {
        const int b = d;
        const float* xb = x + (size_t)b * TLEN;
        const int a0 = 512 * HOP - PADL;
#pragma unroll
        for (int it = 0; it < 4; ++it) {
            const int n = tid + it * 512;
            const float w  = window[n];
            const float va = xb[refl(a0 + n)] * w;
            const float vb = xb[refl(a0 + HOP + n)] * w;   // phantom frame, unused
            z[0][pidx(brev11(n))] = make_float2(va, vb);
        }
        __syncthreads();
        if (tid < 256) octet_pass<1, 0>(z[0], tid);
        __syncthreads();
        if (tid < 256) octet_pass<8, 3>(z[0], tid);
        __syncthreads();
        if (tid < 256) octet_pass<64, 6>(z[0], tid);
        __syncthreads();
        quad_item(z[0], tid & 511);
        __syncthreads();
#pragma unroll
        for (int it = 0; it < 3; ++it) {
            const int k = tid + it * 512;
            if (k < NBINS) {
                const int km = (N_FFT - k) & (N_FFT - 1);
                const float2 zk = z[0][pidx(k)];
                const float2 zr = z[0][pidx(km)];
                const size_t o = ((size_t)b * NBINS + (size_t)k) * NFRAMES + 512;
                outr[o] = 0.5f * (zk.x + zr.x);
                outi[o] = 0.5f * (zk.y - zr.y);
            }
        }
        return;
    }

    // ---------------- main blocks: tiles A=(bA,g) then B=(bA+8,g) -----------
    // XCD swizzle: octets of consecutive g (one 128 B output-line span) get
    // ids differing by 8 (same XCD) in adjacent slots (co-resident).
    const int m    = d - NBATCH;                  // [0,1024); m&7 == d&7
    const int xcd  = m & 7;
    const int slot = m >> 3;                      // [0,128)
    const int O    = (slot >> 3) * 8 + xcd;       // octet id [0,128)
    const int L0   = O * 8 + (slot & 7);          // logical tile [0,1024)
    const int bA   = L0 >> 7;                     // [0,8)
    const int g    = L0 & 127;
    const int bB   = bA + 8;                      // [8,16)
    const int f0   = g * 4;

    const float* xA = x + (size_t)bA * TLEN;
    const float* xB = x + (size_t)bB * TLEN;

    float w_p[8], pa[8], pb[8];

    // ---- tile A load (coalesced, R9 pattern); save window values ----
#pragma unroll
    for (int it = 0; it < 8; ++it) {
        const int idx = tid + it * 512;           // [0,4096)
        const int c   = idx >> 11;
        const int n   = idx & 2047;
        const int fa  = f0 + 2 * c;
        const float w = window[n];
        w_p[it] = w;
        const float va = xA[refl(fa * HOP - PADL + n)] * w;
        const float vb = xA[refl((fa + 1) * HOP - PADL + n)] * w;
        z[c][pidx(brev11(n))] = make_float2(va, vb);
    }
    __syncthreads();

    // ---- tile B prefetch into registers (fire-and-forget; latency hides
    //      under tile A's entire FFT + epilogue) ----
#pragma unroll
    for (int it = 0; it < 8; ++it) {
        const int idx = tid + it * 512;
        const int c   = idx >> 11;
        const int n   = idx & 2047;
        const int fa  = f0 + 2 * c;
        pa[it] = xB[refl(fa * HOP - PADL + n)];
        pb[it] = xB[refl((fa + 1) * HOP - PADL + n)];
    }

    // ---- FFT A + epilogue A (stores drain during FFT B) ----
    fft_main(z, tid);
    epi_main(z, outr, outi, bA, f0, tid);
    __syncthreads();                              // all reads of z done

    // ---- tile B writeback (compiler inserts the vmcnt wait here) ----
#pragma unroll
    for (int it = 0; it < 8; ++it) {
        const int idx = tid + it * 512;
        const int c   = idx >> 11;
        const int n   = idx & 2047;
        z[c][pidx(brev11(n))] = make_float2(pa[it] * w_p[it], pb[it] * w_p[it]);
    }
    __syncthreads();

    // ---- FFT B + epilogue B ----
    fft_main(z, tid);
    epi_main(z, outr, outi, bB, f0, tid);
}

extern "C" void kernel_launch(void* const* d_in, const int* in_sizes, int n_in,
                              void* d_out, int out_size, void* d_ws, size_t ws_size,
                              hipStream_t stream) {
    const float* x      = (const float*)d_in[0];
    const float* window = (const float*)d_in[1];
    float* out          = (float*)d_out;

    dim3 grid(1040);   // 16 tail (first) + 1024 main; d_ws deliberately unused
    stft_one<<<grid, 512, 0, stream>>>(x, window, out);
}

// Round 5
// 127.635 us; speedup vs baseline: 1.3420x; 1.3420x over previous
//
#include <hip/hip_runtime.h>

// STFT: x[16, 262144] fp32, Hann 2048, hop 512, reflect pad 1024.
// Output: real[16,1025,513] ++ imag[16,1025,513], fp32.
//
// Round 12: two-tile pipeline, register-free prefetch. R11's register
// prefetch spilled to scratch (VGPR=32, FETCH 9.5->91 MB, WRITE 95->300 MB:
// the smoking gun) and serialized everything through HBM. Same pipeline idea,
// correct mechanism:
//  - Tile B's 4 frames overlap (hop 512 < win 2048): union = ONE contiguous
//    span of 3584 floats (14.3 KB). Prefetch it raw into LDS with
//    __builtin_amdgcn_global_load_lds (async DMA, zero data registers,
//    per-lane global source address handles refl() at edges, LDS dest is
//    wave-uniform-base + lane*4 as required).
//  - Issue right after tile A's load barrier; latency hides under tile A's
//    FFT + epilogue. The __syncthreads() after epilogue A drains vmcnt(0)
//    => staged data visible. Writeback = window multiply + bit-reverse
//    scatter from LDS (va=stage[1024c+n], vb=stage[1024c+512+n]).
//  - Tile A's scattered stores drain under FFT B.
//  - LDS 33.8+14.3 = 48.1 KB -> 3 blocks/CU (24 waves): trading 25%
//    residency for hiding the load phase. __launch_bounds__(512,6).
//  - FFT core / loader A / epilogue exactly R9 (best known: 49 us).
//  - Grid 1040 = 16 tail blocks FIRST (frame 512) + 1024 main (tiles
//    A=(bA,g), B=(bA+8,g)); octet XCD swizzle for write merging kept.

#define N_FFT   2048
#define LOG2N   11
#define HOP     512
#define PADL    1024
#define NBINS   1025
#define NFRAMES 513
#define NBATCH  16
#define TLEN    262144

#define HALF_OUT ((size_t)NBATCH * NBINS * NFRAMES)   // 8,413,200 floats per plane

__device__ __forceinline__ int pidx(int a) { return a + (a >> 5); }

__device__ __forceinline__ int refl(int j) {
    if (j < 0)          j = -j;
    else if (j >= TLEN) j = 2 * TLEN - 2 - j;
    return j;
}

__device__ __forceinline__ int brev11(int n) {
    return (int)(__brev((unsigned)n) >> 21);
}

__device__ __forceinline__ float2 cmul(float2 a, float2 w) {
    return make_float2(fmaf(a.x, w.x, -a.y * w.y), fmaf(a.x, w.y, a.y * w.x));
}
__device__ __forceinline__ float2 cadd(float2 a, float2 b) {
    return make_float2(a.x + b.x, a.y + b.y);
}
__device__ __forceinline__ float2 csub(float2 a, float2 b) {
    return make_float2(a.x - b.x, a.y - b.y);
}
__device__ __forceinline__ float2 csqr(float2 w) {
    return make_float2(fmaf(w.x, w.x, -w.y * w.y), 2.0f * w.x * w.y);
}

// Three DIT stages (halves H, 2H, 4H) on points base + m*H, m=0..7, in registers.
template <int H, int L2H>
__device__ __forceinline__ void octet_pass(float2* __restrict__ zc, int q) {
    const int p    = q & (H - 1);
    const int base = ((q >> L2H) << (L2H + 3)) + p;
    int ia[8];
#pragma unroll
    for (int m = 0; m < 8; ++m) ia[m] = pidx(base + m * H);
    float2 v0 = zc[ia[0]], v1 = zc[ia[1]], v2 = zc[ia[2]], v3 = zc[ia[3]];
    float2 v4 = zc[ia[4]], v5 = zc[ia[5]], v6 = zc[ia[6]], v7 = zc[ia[7]];

    float2 w1, w2, w3;
    if (H == 1) {
        w3 = make_float2(1.0f, 0.0f); w2 = w3; w1 = w3;   // p==0 always
    } else {
        float s, c;
        __sincosf((float)p * (-3.14159265358979323846f / (4.0f * (float)H)), &s, &c);
        w3 = make_float2(c, s);
        w2 = csqr(w3);
        w1 = csqr(w2);
    }

    float2 t;
    // stage A (half=H): pairs (0,1)(2,3)(4,5)(6,7), all twiddle w1
    t = cmul(v1, w1); v1 = csub(v0, t); v0 = cadd(v0, t);
    t = cmul(v3, w1); v3 = csub(v2, t); v2 = cadd(v2, t);
    t = cmul(v5, w1); v5 = csub(v4, t); v4 = cadd(v4, t);
    t = cmul(v7, w1); v7 = csub(v6, t); v6 = cadd(v6, t);
    // stage B (half=2H): pairs (0,2)(4,6) w2 ; (1,3)(5,7) -i*w2
    const float2 w2m = make_float2(w2.y, -w2.x);
    t = cmul(v2, w2);  v2 = csub(v0, t); v0 = cadd(v0, t);
    t = cmul(v3, w2m); v3 = csub(v1, t); v1 = cadd(v1, t);
    t = cmul(v6, w2);  v6 = csub(v4, t); v4 = cadd(v4, t);
    t = cmul(v7, w2m); v7 = csub(v5, t); v5 = cadd(v5, t);
    // stage C (half=4H): pairs (0,4) w3 ; (1,5) w3*e^{-i pi/4} ; (2,6) -i*w3 ; (3,7) -i*w3*e^{-i pi/4}
    const float R = 0.70710678118654752f;
    const float2 w3o  = make_float2((w3.x + w3.y) * R, (w3.y - w3.x) * R);
    const float2 w3m  = make_float2(w3.y, -w3.x);
    const float2 w3mo = make_float2(w3o.y, -w3o.x);
    t = cmul(v4, w3);   v4 = csub(v0, t); v0 = cadd(v0, t);
    t = cmul(v5, w3o);  v5 = csub(v1, t); v1 = cadd(v1, t);
    t = cmul(v6, w3m);  v6 = csub(v2, t); v2 = cadd(v2, t);
    t = cmul(v7, w3mo); v7 = csub(v3, t); v3 = cadd(v3, t);

    zc[ia[0]] = v0; zc[ia[1]] = v1; zc[ia[2]] = v2; zc[ia[3]] = v3;
    zc[ia[4]] = v4; zc[ia[5]] = v5; zc[ia[6]] = v6; zc[ia[7]] = v7;
}

// Radix-4 quad item (stages 10-11, h=512) on plane zc, position p in [0,512).
__device__ __forceinline__ void quad_item(float2* __restrict__ zc, int p) {
    float s, cc;
    __sincosf((float)p * (-3.14159265358979323846f / 1024.0f), &s, &cc);
    const float2 w2  = make_float2(cc, s);        // exp(-i*pi*p/1024)
    const float2 w1  = csqr(w2);                  // exp(-i*pi*p/512)
    const float2 w2m = make_float2(w2.y, -w2.x);  // -i*w2
    const int i0 = pidx(p), i1 = pidx(p + 512), i2 = pidx(p + 1024), i3 = pidx(p + 1536);
    float2 v0 = zc[i0], v1 = zc[i1], v2 = zc[i2], v3 = zc[i3];
    float2 t;
    t = cmul(v1, w1); v1 = csub(v0, t); v0 = cadd(v0, t);
    t = cmul(v3, w1); v3 = csub(v2, t); v2 = cadd(v2, t);
    t = cmul(v2, w2);  v2 = csub(v0, t); v0 = cadd(v0, t);
    t = cmul(v3, w2m); v3 = csub(v1, t); v1 = cadd(v1, t);
    zc[i0] = v0; zc[i1] = v1; zc[i2] = v2; zc[i3] = v3;
}

// Full FFT on both planes (enter with loader data in z, after a barrier).
// 4 internal barriers; leaves results in z, barrier at end included.
__device__ __forceinline__ void fft_main(float2 (*__restrict__ z)[2113], int tid) {
    const int c = tid >> 8, q = tid & 255;
    octet_pass<1, 0>(z[c], q);  __syncthreads();
    octet_pass<8, 3>(z[c], q);  __syncthreads();
    octet_pass<64, 6>(z[c], q); __syncthreads();
    quad_item(z[0], tid & 511);
    quad_item(z[1], tid & 511);
    __syncthreads();
}

// Conjugate-symmetry unpack + direct write of 4 frames (f0..f0+3) of batch b.
__device__ __forceinline__ void epi_main(const float2 (*__restrict__ z)[2113],
                                         float* __restrict__ outr,
                                         float* __restrict__ outi,
                                         int b, int f0, int tid) {
#pragma unroll
    for (int it = 0; it < 3; ++it) {
        const int k = tid + it * 512;
        if (k < NBINS) {
            const int km = (N_FFT - k) & (N_FFT - 1);
            const float2 zk0 = z[0][pidx(k)];
            const float2 zr0 = z[0][pidx(km)];
            const float2 zk1 = z[1][pidx(k)];
            const float2 zr1 = z[1][pidx(km)];
            const size_t o = ((size_t)b * NBINS + (size_t)k) * NFRAMES + (size_t)f0;
            outr[o + 0] = 0.5f * (zk0.x + zr0.x);   // even frame re
            outr[o + 1] = 0.5f * (zk0.y + zr0.y);   // odd frame re
            outr[o + 2] = 0.5f * (zk1.x + zr1.x);
            outr[o + 3] = 0.5f * (zk1.y + zr1.y);
            outi[o + 0] = 0.5f * (zk0.y - zr0.y);   // even frame im
            outi[o + 1] = 0.5f * (zr0.x - zk0.x);   // odd frame im
            outi[o + 2] = 0.5f * (zk1.y - zr1.y);
            outi[o + 3] = 0.5f * (zr1.x - zk1.x);
        }
    }
}

__global__ __launch_bounds__(512, 6) void stft_one(
    const float* __restrict__ x,
    const float* __restrict__ window,
    float* __restrict__ out)
{
    __shared__ float2 z[2][2113];     // 33,808 B
    __shared__ float  stage[3584];    // 14,336 B raw B-tile span -> 48.1 KB total

    const int d   = blockIdx.x;
    const int tid = threadIdx.x;
    float* __restrict__ outr = out;
    float* __restrict__ outi = out + HALF_OUT;

    // ---------------- tail blocks: frame 512 of batch d, run first ----------
    if (d < NBATCH) {
        const int b = d;
        const float* xb = x + (size_t)b * TLEN;
        const int a0 = 512 * HOP - PADL;
#pragma unroll
        for (int it = 0; it < 4; ++it) {
            const int n = tid + it * 512;
            const float w  = window[n];
            const float va = xb[refl(a0 + n)] * w;
            const float vb = xb[refl(a0 + HOP + n)] * w;   // phantom frame, unused
            z[0][pidx(brev11(n))] = make_float2(va, vb);
        }
        __syncthreads();
        if (tid < 256) octet_pass<1, 0>(z[0], tid);
        __syncthreads();
        if (tid < 256) octet_pass<8, 3>(z[0], tid);
        __syncthreads();
        if (tid < 256) octet_pass<64, 6>(z[0], tid);
        __syncthreads();
        quad_item(z[0], tid & 511);
        __syncthreads();
#pragma unroll
        for (int it = 0; it < 3; ++it) {
            const int k = tid + it * 512;
            if (k < NBINS) {
                const int km = (N_FFT - k) & (N_FFT - 1);
                const float2 zk = z[0][pidx(k)];
                const float2 zr = z[0][pidx(km)];
                const size_t o = ((size_t)b * NBINS + (size_t)k) * NFRAMES + 512;
                outr[o] = 0.5f * (zk.x + zr.x);
                outi[o] = 0.5f * (zk.y - zr.y);
            }
        }
        return;
    }

    // ---------------- main blocks: tiles A=(bA,g) then B=(bA+8,g) -----------
    // XCD swizzle: octets of consecutive g (one 128 B output-line span) get
    // ids differing by 8 (same XCD) in adjacent slots (co-resident).
    const int m    = d - NBATCH;                  // [0,1024); m&7 == d&7
    const int xcd  = m & 7;
    const int slot = m >> 3;                      // [0,128)
    const int O    = (slot >> 3) * 8 + xcd;       // octet id [0,128)
    const int L0   = O * 8 + (slot & 7);          // logical tile [0,1024)
    const int bA   = L0 >> 7;                     // [0,8)
    const int g    = L0 & 127;
    const int bB   = bA + 8;                      // [8,16)
    const int f0   = g * 4;

    const float* xA = x + (size_t)bA * TLEN;
    const float* xB = x + (size_t)bB * TLEN;

    // ---- tile A load (coalesced, R9 pattern) ----
#pragma unroll
    for (int it = 0; it < 8; ++it) {
        const int idx = tid + it * 512;           // [0,4096)
        const int c   = idx >> 11;
        const int n   = idx & 2047;
        const int fa  = f0 + 2 * c;
        const float w = window[n];
        const float va = xA[refl(fa * HOP - PADL + n)] * w;
        const float vb = xA[refl((fa + 1) * HOP - PADL + n)] * w;
        z[c][pidx(brev11(n))] = make_float2(va, vb);
    }
    __syncthreads();

    // ---- tile B prefetch: raw span x[a0s .. a0s+3584) -> stage[], async,
    //      zero registers. Per-lane global address handles refl(); LDS dest
    //      is wave-uniform base + lane*4 as required. ----
    {
        const int a0s = f0 * HOP - PADL;          // span start (frames f0..f0+3)
#pragma unroll
        for (int it = 0; it < 7; ++it) {
            const int p = tid + it * 512;         // [0,3584)
            const float* src = xB + refl(a0s + p);
            __builtin_amdgcn_global_load_lds(
                (const __attribute__((address_space(1))) void*)src,
                (__attribute__((address_space(3))) void*)&stage[p],
                4, 0, 0);
        }
    }

    // ---- FFT A + epilogue A (B prefetch in flight underneath) ----
    fft_main(z, tid);
    epi_main(z, outr, outi, bA, f0, tid);
    __syncthreads();   // drains vmcnt(0): stage[] complete; z reads done

    // ---- tile B writeback: window + bit-reverse scatter from stage ----
    // va = stage[1024c + n], vb = stage[1024c + 512 + n] (lane-consecutive)
#pragma unroll
    for (int it = 0; it < 8; ++it) {
        const int idx = tid + it * 512;
        const int c   = idx >> 11;
        const int n   = idx & 2047;
        const float w = window[n];
        const float va = stage[1024 * c + n] * w;
        const float vb = stage[1024 * c + 512 + n] * w;
        z[c][pidx(brev11(n))] = make_float2(va, vb);
    }
    __syncthreads();

    // ---- FFT B + epilogue B (tile A stores drain underneath) ----
    fft_main(z, tid);
    epi_main(z, outr, outi, bB, f0, tid);
}

extern "C" void kernel_launch(void* const* d_in, const int* in_sizes, int n_in,
                              void* d_out, int out_size, void* d_ws, size_t ws_size,
                              hipStream_t stream) {
    const float* x      = (const float*)d_in[0];
    const float* window = (const float*)d_in[1];
    float* out          = (float*)d_out;

    dim3 grid(1040);   // 16 tail (first) + 1024 main; d_ws deliberately unused
    stft_one<<<grid, 512, 0, stream>>>(x, window, out);
}

// Round 8
// 104.198 us; speedup vs baseline: 1.6439x; 1.2249x over previous
//
#include <hip/hip_runtime.h>

// STFT: x[16, 262144] fp32, Hann 2048, hop 512, reflect pad 1024.
// Output: real[16,1025,513] ++ imag[16,1025,513], fp32.
//
// Round 15 == Round 13 resubmitted (two consecutive infra failures:
// "MI355X container failed twice"; no kernel verdict either time).
// Audited for container-killing defects: no divergent barriers, no OOB
// (interior span [1024,260607] in bounds; window float4 reads end at 2047),
// no register pathology (~40 VGPR vs 64 cap). Unchanged source, third run.
//
// R13 rationale: revert to R9 (proven 49 us: 512 thr, 2 planes, 33.8 KB LDS,
// 4 blocks/CU, octet XCD swizzle) + VALU/VMEM diet. R10/R11/R12 all tried to
// overlap the load phase structurally and all regressed (convoy effect /
// register spill / L2+occupancy side effects). This round keeps the R9 phase
// structure bit-identical and removes wasted work:
//  - float4 loader for interior blocks (g in [1,126]): refl() is provably
//    dead there (span [1024, 260607] in bounds), all loads 16B-aligned;
//    brev11(4j+u) = brev9(j) + {0,1024,512,1536}[u] so the bit-reversed
//    scatter costs one brev per 4 samples. 16 scalar x-loads + 16 window
//    loads -> 4+2 dwordx4 loads; ~60% of loader VALU removed.
//  - g==0 / g==127 / tail keep the scalar refl path (wave-uniform branch).
//  - Quad pass: one __sincosf shared by both planes (same p).
//  - Tail blocks (frame 512) moved to grid front so they don't straggle.

#define N_FFT   2048
#define LOG2N   11
#define HOP     512
#define PADL    1024
#define NBINS   1025
#define NFRAMES 513
#define NBATCH  16
#define TLEN    262144

#define HALF_OUT ((size_t)NBATCH * NBINS * NFRAMES)   // 8,413,200 floats per plane

__device__ __forceinline__ int pidx(int a) { return a + (a >> 5); }

__device__ __forceinline__ int refl(int j) {
    if (j < 0)          j = -j;
    else if (j >= TLEN) j = 2 * TLEN - 2 - j;
    return j;
}

__device__ __forceinline__ int brev11(int n) {
    return (int)(__brev((unsigned)n) >> 21);
}

__device__ __forceinline__ float2 cmul(float2 a, float2 w) {
    return make_float2(fmaf(a.x, w.x, -a.y * w.y), fmaf(a.x, w.y, a.y * w.x));
}
__device__ __forceinline__ float2 cadd(float2 a, float2 b) {
    return make_float2(a.x + b.x, a.y + b.y);
}
__device__ __forceinline__ float2 csub(float2 a, float2 b) {
    return make_float2(a.x - b.x, a.y - b.y);
}
__device__ __forceinline__ float2 csqr(float2 w) {
    return make_float2(fmaf(w.x, w.x, -w.y * w.y), 2.0f * w.x * w.y);
}

// Three DIT stages (halves H, 2H, 4H) on points base + m*H, m=0..7, in registers.
template <int H, int L2H>
__device__ __forceinline__ void octet_pass(float2* __restrict__ zc, int q) {
    const int p    = q & (H - 1);
    const int base = ((q >> L2H) << (L2H + 3)) + p;
    int ia[8];
#pragma unroll
    for (int m = 0; m < 8; ++m) ia[m] = pidx(base + m * H);
    float2 v0 = zc[ia[0]], v1 = zc[ia[1]], v2 = zc[ia[2]], v3 = zc[ia[3]];
    float2 v4 = zc[ia[4]], v5 = zc[ia[5]], v6 = zc[ia[6]], v7 = zc[ia[7]];

    float2 w1, w2, w3;
    if (H == 1) {
        w3 = make_float2(1.0f, 0.0f); w2 = w3; w1 = w3;   // p==0 always
    } else {
        float s, c;
        __sincosf((float)p * (-3.14159265358979323846f / (4.0f * (float)H)), &s, &c);
        w3 = make_float2(c, s);
        w2 = csqr(w3);
        w1 = csqr(w2);
    }

    float2 t;
    // stage A (half=H): pairs (0,1)(2,3)(4,5)(6,7), all twiddle w1
    t = cmul(v1, w1); v1 = csub(v0, t); v0 = cadd(v0, t);
    t = cmul(v3, w1); v3 = csub(v2, t); v2 = cadd(v2, t);
    t = cmul(v5, w1); v5 = csub(v4, t); v4 = cadd(v4, t);
    t = cmul(v7, w1); v7 = csub(v6, t); v6 = cadd(v6, t);
    // stage B (half=2H): pairs (0,2)(4,6) w2 ; (1,3)(5,7) -i*w2
    const float2 w2m = make_float2(w2.y, -w2.x);
    t = cmul(v2, w2);  v2 = csub(v0, t); v0 = cadd(v0, t);
    t = cmul(v3, w2m); v3 = csub(v1, t); v1 = cadd(v1, t);
    t = cmul(v6, w2);  v6 = csub(v4, t); v4 = cadd(v4, t);
    t = cmul(v7, w2m); v7 = csub(v5, t); v5 = cadd(v5, t);
    // stage C (half=4H): pairs (0,4) w3 ; (1,5) w3*e^{-i pi/4} ; (2,6) -i*w3 ; (3,7) -i*w3*e^{-i pi/4}
    const float R = 0.70710678118654752f;
    const float2 w3o  = make_float2((w3.x + w3.y) * R, (w3.y - w3.x) * R);
    const float2 w3m  = make_float2(w3.y, -w3.x);
    const float2 w3mo = make_float2(w3o.y, -w3o.x);
    t = cmul(v4, w3);   v4 = csub(v0, t); v0 = cadd(v0, t);
    t = cmul(v5, w3o);  v5 = csub(v1, t); v1 = cadd(v1, t);
    t = cmul(v6, w3m);  v6 = csub(v2, t); v2 = cadd(v2, t);
    t = cmul(v7, w3mo); v7 = csub(v3, t); v3 = cadd(v3, t);

    zc[ia[0]] = v0; zc[ia[1]] = v1; zc[ia[2]] = v2; zc[ia[3]] = v3;
    zc[ia[4]] = v4; zc[ia[5]] = v5; zc[ia[6]] = v6; zc[ia[7]] = v7;
}

// Radix-4 quad item (stages 10-11, h=512), twiddles precomputed by caller.
__device__ __forceinline__ void quad_core(float2* __restrict__ zc, int p,
                                          float2 w1, float2 w2, float2 w2m) {
    const int i0 = pidx(p), i1 = pidx(p + 512), i2 = pidx(p + 1024), i3 = pidx(p + 1536);
    float2 v0 = zc[i0], v1 = zc[i1], v2 = zc[i2], v3 = zc[i3];
    float2 t;
    t = cmul(v1, w1); v1 = csub(v0, t); v0 = cadd(v0, t);
    t = cmul(v3, w1); v3 = csub(v2, t); v2 = cadd(v2, t);
    t = cmul(v2, w2);  v2 = csub(v0, t); v0 = cadd(v0, t);
    t = cmul(v3, w2m); v3 = csub(v1, t); v1 = cadd(v1, t);
    zc[i0] = v0; zc[i1] = v1; zc[i2] = v2; zc[i3] = v3;
}

__global__ __launch_bounds__(512, 8) void stft_one(
    const float* __restrict__ x,
    const float* __restrict__ window,
    float* __restrict__ out)
{
    __shared__ float2 z[2][2113];     // 33,808 B -> 4 blocks/CU

    const int d   = blockIdx.x;
    const int tid = threadIdx.x;
    float* __restrict__ outr = out;
    float* __restrict__ outi = out + HALF_OUT;

    // ---------------- tail blocks: frame 512 of batch d, run first ----------
    if (d < NBATCH) {
        const int b = d;
        const float* xb = x + (size_t)b * TLEN;
        const int a0 = 512 * HOP - PADL;
#pragma unroll
        for (int it = 0; it < 4; ++it) {
            const int n = tid + it * 512;
            const float w  = window[n];
            const float va = xb[refl(a0 + n)] * w;
            const float vb = xb[refl(a0 + HOP + n)] * w;   // phantom frame, unused
            z[0][pidx(brev11(n))] = make_float2(va, vb);
        }
        __syncthreads();
        if (tid < 256) octet_pass<1, 0>(z[0], tid);
        __syncthreads();
        if (tid < 256) octet_pass<8, 3>(z[0], tid);
        __syncthreads();
        if (tid < 256) octet_pass<64, 6>(z[0], tid);
        __syncthreads();
        {
            float s, cc;
            __sincosf((float)tid * (-3.14159265358979323846f / 1024.0f), &s, &cc);
            const float2 w2  = make_float2(cc, s);
            const float2 w1  = csqr(w2);
            const float2 w2m = make_float2(w2.y, -w2.x);
            quad_core(z[0], tid, w1, w2, w2m);
        }
        __syncthreads();
#pragma unroll
        for (int it = 0; it < 3; ++it) {
            const int k = tid + it * 512;
            if (k < NBINS) {
                const int km = (N_FFT - k) & (N_FFT - 1);
                const float2 zk = z[0][pidx(k)];
                const float2 zr = z[0][pidx(km)];
                const size_t o = ((size_t)b * NBINS + (size_t)k) * NFRAMES + 512;
                outr[o] = 0.5f * (zk.x + zr.x);
                outi[o] = 0.5f * (zk.y - zr.y);
            }
        }
        return;
    }

    // ---------------- main blocks ----------------
    // XCD swizzle (R9): octets of consecutive g (one 128 B output-line span)
    // get ids differing by 8 (same XCD) in adjacent slots (co-resident).
    const int m    = d - NBATCH;                  // [0,2048)
    const int xcd  = m & 7;
    const int slot = m >> 3;                      // [0,256)
    const int O    = (slot >> 3) * 8 + xcd;       // octet id [0,256)
    const int L    = O * 8 + (slot & 7);          // logical block [0,2048)
    const int b    = L >> 7;
    const int g    = L & 127;
    const int f0   = g * 4;

    const float* xb = x + (size_t)b * TLEN;

    // ---- load 4 windowed frames (2 planes), bit-reversed ----
    if (g >= 1 && g <= 126) {
        // interior: refl() dead (span [1024, 260607]); all 16B-aligned.
#pragma unroll
        for (int it = 0; it < 2; ++it) {
            const int idx = tid + it * 512;       // [0,1024)
            const int c   = idx >> 9;
            const int j   = idx & 511;
            const int n0  = j << 2;
            const int a0  = (f0 + 2 * c) * HOP - PADL;
            const float4 w4 = *reinterpret_cast<const float4*>(&window[n0]);
            const float4 a4 = *reinterpret_cast<const float4*>(&xb[a0 + n0]);
            const float4 b4 = *reinterpret_cast<const float4*>(&xb[a0 + HOP + n0]);
            const int r0 = (int)(__brev((unsigned)j) >> 23);   // brev9(j)
            // brev11(4j+u) = brev9(j) + {0,1024,512,1536}[u]
            z[c][pidx(r0)]        = make_float2(a4.x * w4.x, b4.x * w4.x);
            z[c][pidx(r0 + 1024)] = make_float2(a4.y * w4.y, b4.y * w4.y);
            z[c][pidx(r0 + 512)]  = make_float2(a4.z * w4.z, b4.z * w4.z);
            z[c][pidx(r0 + 1536)] = make_float2(a4.w * w4.w, b4.w * w4.w);
        }
    } else {
        // edge blocks (g==0, g==127): scalar refl path (R9 loader)
#pragma unroll
        for (int it = 0; it < 8; ++it) {
            const int idx = tid + it * 512;       // [0,4096)
            const int c   = idx >> 11;
            const int n   = idx & 2047;
            const int fa  = f0 + 2 * c;
            const float w  = window[n];
            const float va = xb[refl(fa * HOP - PADL + n)] * w;
            const float vb = xb[refl((fa + 1) * HOP - PADL + n)] * w;
            z[c][pidx(brev11(n))] = make_float2(va, vb);
        }
    }
    __syncthreads();

    // ---- stages 1-9: three radix-8 register trips ----
    {
        const int c = tid >> 8, q = tid & 255;
        octet_pass<1, 0>(z[c], q);  __syncthreads();
        octet_pass<8, 3>(z[c], q);  __syncthreads();
        octet_pass<64, 6>(z[c], q); __syncthreads();
    }

    // ---- stages 10-11: radix-4 quad pass (h=512), twiddles shared ----
    {
        const int p = tid;                        // [0,512)
        float s, cc;
        __sincosf((float)p * (-3.14159265358979323846f / 1024.0f), &s, &cc);
        const float2 w2  = make_float2(cc, s);    // exp(-i*pi*p/1024)
        const float2 w1  = csqr(w2);              // exp(-i*pi*p/512)
        const float2 w2m = make_float2(w2.y, -w2.x);
        quad_core(z[0], p, w1, w2, w2m);
        quad_core(z[1], p, w1, w2, w2m);
    }
    __syncthreads();

    // ---- unpack + direct write: 16 B chunk per k-row ----
#pragma unroll
    for (int it = 0; it < 3; ++it) {
        const int k = tid + it * 512;
        if (k < NBINS) {
            const int km = (N_FFT - k) & (N_FFT - 1);
            const float2 zk0 = z[0][pidx(k)];
            const float2 zr0 = z[0][pidx(km)];
            const float2 zk1 = z[1][pidx(k)];
            const float2 zr1 = z[1][pidx(km)];
            const size_t o = ((size_t)b * NBINS + (size_t)k) * NFRAMES + (size_t)f0;
            outr[o + 0] = 0.5f * (zk0.x + zr0.x);   // even frame re
            outr[o + 1] = 0.5f * (zk0.y + zr0.y);   // odd frame re
            outr[o + 2] = 0.5f * (zk1.x + zr1.x);
            outr[o + 3] = 0.5f * (zk1.y + zr1.y);
            outi[o + 0] = 0.5f * (zk0.y - zr0.y);   // even frame im
            outi[o + 1] = 0.5f * (zr0.x - zk0.x);   // odd frame im
            outi[o + 2] = 0.5f * (zk1.y - zr1.y);
            outi[o + 3] = 0.5f * (zr1.x - zk1.x);
        }
    }
}

extern "C" void kernel_launch(void* const* d_in, const int* in_sizes, int n_in,
                              void* d_out, int out_size, void* d_ws, size_t ws_size,
                              hipStream_t stream) {
    const float* x      = (const float*)d_in[0];
    const float* window = (const float*)d_in[1];
    float* out          = (float*)d_out;

    dim3 grid(2064);   // 16 tail (first) + 2048 main; d_ws deliberately unused
    stft_one<<<grid, 512, 0, stream>>>(x, window, out);
}

// Round 9
// 103.565 us; speedup vs baseline: 1.6539x; 1.0061x over previous
//
#include <hip/hip_runtime.h>

// STFT: x[16, 262144] fp32, Hann 2048, hop 512, reflect pad 1024.
// Output: real[16,1025,513] ++ imag[16,1025,513], fp32.
//
// Round 16: fused quad+epilogue on top of R13/R15 (verified 42.7 us kernel).
// R15 confirmed the VALU-diet theory (49 -> 42.7, clean traffic). Pipes are
// still ~serialized (VALU 12us + HBM 15us + LDS 10us ~= 42.7 measured), and
// structural overlap attempts failed 3x, so keep dieting:
//  - Stages 10-11 (radix-4, h=512) keep X[p], X[p+512] in REGISTERS; only
//    v2/v3 (X[p+1024], X[p+1536]) go to LDS (owner-private slots, race-free)
//    for the conjugate-partner exchange (partner thread 512-p needs them).
//  - Epilogue fused: thread p>=1 stores rows k=p and k=p+512 directly from
//    registers + 2 partner reads/plane; thread 0 stores k=0,512,1024 from
//    its own regs. Removes the full X materialization + re-read phase:
//    LDS ops 80 -> 72/thread, store instrs 17 scalar -> 4 dwordx4
//    (aligned(4) ext_vector: rows are only 4B-aligned).
//  - Everything else identical to R15: float4 interior loader (refl provably
//    dead, brev11(4j+u) = brev9(j)+{0,1024,512,1536}[u]), scalar edge loader,
//    3 radix-8 octet trips, octet XCD swizzle, tail blocks first.

#define N_FFT   2048
#define LOG2N   11
#define HOP     512
#define PADL    1024
#define NBINS   1025
#define NFRAMES 513
#define NBATCH  16
#define TLEN    262144

#define HALF_OUT ((size_t)NBATCH * NBINS * NFRAMES)   // 8,413,200 floats per plane

typedef float f4_t __attribute__((ext_vector_type(4)));
typedef f4_t uf4 __attribute__((aligned(4)));         // 4B-aligned dwordx4

__device__ __forceinline__ int pidx(int a) { return a + (a >> 5); }

__device__ __forceinline__ int refl(int j) {
    if (j < 0)          j = -j;
    else if (j >= TLEN) j = 2 * TLEN - 2 - j;
    return j;
}

__device__ __forceinline__ int brev11(int n) {
    return (int)(__brev((unsigned)n) >> 21);
}

__device__ __forceinline__ float2 cmul(float2 a, float2 w) {
    return make_float2(fmaf(a.x, w.x, -a.y * w.y), fmaf(a.x, w.y, a.y * w.x));
}
__device__ __forceinline__ float2 cadd(float2 a, float2 b) {
    return make_float2(a.x + b.x, a.y + b.y);
}
__device__ __forceinline__ float2 csub(float2 a, float2 b) {
    return make_float2(a.x - b.x, a.y - b.y);
}
__device__ __forceinline__ float2 csqr(float2 w) {
    return make_float2(fmaf(w.x, w.x, -w.y * w.y), 2.0f * w.x * w.y);
}

// Three DIT stages (halves H, 2H, 4H) on points base + m*H, m=0..7, in registers.
template <int H, int L2H>
__device__ __forceinline__ void octet_pass(float2* __restrict__ zc, int q) {
    const int p    = q & (H - 1);
    const int base = ((q >> L2H) << (L2H + 3)) + p;
    int ia[8];
#pragma unroll
    for (int m = 0; m < 8; ++m) ia[m] = pidx(base + m * H);
    float2 v0 = zc[ia[0]], v1 = zc[ia[1]], v2 = zc[ia[2]], v3 = zc[ia[3]];
    float2 v4 = zc[ia[4]], v5 = zc[ia[5]], v6 = zc[ia[6]], v7 = zc[ia[7]];

    float2 w1, w2, w3;
    if (H == 1) {
        w3 = make_float2(1.0f, 0.0f); w2 = w3; w1 = w3;   // p==0 always
    } else {
        float s, c;
        __sincosf((float)p * (-3.14159265358979323846f / (4.0f * (float)H)), &s, &c);
        w3 = make_float2(c, s);
        w2 = csqr(w3);
        w1 = csqr(w2);
    }

    float2 t;
    // stage A (half=H): pairs (0,1)(2,3)(4,5)(6,7), all twiddle w1
    t = cmul(v1, w1); v1 = csub(v0, t); v0 = cadd(v0, t);
    t = cmul(v3, w1); v3 = csub(v2, t); v2 = cadd(v2, t);
    t = cmul(v5, w1); v5 = csub(v4, t); v4 = cadd(v4, t);
    t = cmul(v7, w1); v7 = csub(v6, t); v6 = cadd(v6, t);
    // stage B (half=2H): pairs (0,2)(4,6) w2 ; (1,3)(5,7) -i*w2
    const float2 w2m = make_float2(w2.y, -w2.x);
    t = cmul(v2, w2);  v2 = csub(v0, t); v0 = cadd(v0, t);
    t = cmul(v3, w2m); v3 = csub(v1, t); v1 = cadd(v1, t);
    t = cmul(v6, w2);  v6 = csub(v4, t); v4 = cadd(v4, t);
    t = cmul(v7, w2m); v7 = csub(v5, t); v5 = cadd(v5, t);
    // stage C (half=4H): pairs (0,4) w3 ; (1,5) w3*e^{-i pi/4} ; (2,6) -i*w3 ; (3,7) -i*w3*e^{-i pi/4}
    const float R = 0.70710678118654752f;
    const float2 w3o  = make_float2((w3.x + w3.y) * R, (w3.y - w3.x) * R);
    const float2 w3m  = make_float2(w3.y, -w3.x);
    const float2 w3mo = make_float2(w3o.y, -w3o.x);
    t = cmul(v4, w3);   v4 = csub(v0, t); v0 = cadd(v0, t);
    t = cmul(v5, w3o);  v5 = csub(v1, t); v1 = cadd(v1, t);
    t = cmul(v6, w3m);  v6 = csub(v2, t); v2 = cadd(v2, t);
    t = cmul(v7, w3mo); v7 = csub(v3, t); v3 = cadd(v3, t);

    zc[ia[0]] = v0; zc[ia[1]] = v1; zc[ia[2]] = v2; zc[ia[3]] = v3;
    zc[ia[4]] = v4; zc[ia[5]] = v5; zc[ia[6]] = v6; zc[ia[7]] = v7;
}

// Radix-4 quad item (stages 10-11, h=512), twiddles precomputed by caller.
// (Used by the tail path only.)
__device__ __forceinline__ void quad_core(float2* __restrict__ zc, int p,
                                          float2 w1, float2 w2, float2 w2m) {
    const int i0 = pidx(p), i1 = pidx(p + 512), i2 = pidx(p + 1024), i3 = pidx(p + 1536);
    float2 v0 = zc[i0], v1 = zc[i1], v2 = zc[i2], v3 = zc[i3];
    float2 t;
    t = cmul(v1, w1); v1 = csub(v0, t); v0 = cadd(v0, t);
    t = cmul(v3, w1); v3 = csub(v2, t); v2 = cadd(v2, t);
    t = cmul(v2, w2);  v2 = csub(v0, t); v0 = cadd(v0, t);
    t = cmul(v3, w2m); v3 = csub(v1, t); v1 = cadd(v1, t);
    zc[i0] = v0; zc[i1] = v1; zc[i2] = v2; zc[i3] = v3;
}

// One output row (4 frames) from zk/zr pairs of both planes.
__device__ __forceinline__ void store_row(float* __restrict__ pr,
                                          float* __restrict__ pi,
                                          float2 zk0, float2 zr0,
                                          float2 zk1, float2 zr1) {
    uf4 re, im;
    re.x = 0.5f * (zk0.x + zr0.x);   // even frame re
    re.y = 0.5f * (zk0.y + zr0.y);   // odd frame re
    re.z = 0.5f * (zk1.x + zr1.x);
    re.w = 0.5f * (zk1.y + zr1.y);
    im.x = 0.5f * (zk0.y - zr0.y);   // even frame im
    im.y = 0.5f * (zr0.x - zk0.x);   // odd frame im
    im.z = 0.5f * (zk1.y - zr1.y);
    im.w = 0.5f * (zr1.x - zk1.x);
    *reinterpret_cast<uf4*>(pr) = re;
    *reinterpret_cast<uf4*>(pi) = im;
}

__global__ __launch_bounds__(512, 8) void stft_one(
    const float* __restrict__ x,
    const float* __restrict__ window,
    float* __restrict__ out)
{
    __shared__ float2 z[2][2113];     // 33,808 B -> 4 blocks/CU

    const int d   = blockIdx.x;
    const int tid = threadIdx.x;
    float* __restrict__ outr = out;
    float* __restrict__ outi = out + HALF_OUT;

    // ---------------- tail blocks: frame 512 of batch d, run first ----------
    if (d < NBATCH) {
        const int b = d;
        const float* xb = x + (size_t)b * TLEN;
        const int a0 = 512 * HOP - PADL;
#pragma unroll
        for (int it = 0; it < 4; ++it) {
            const int n = tid + it * 512;
            const float w  = window[n];
            const float va = xb[refl(a0 + n)] * w;
            const float vb = xb[refl(a0 + HOP + n)] * w;   // phantom frame, unused
            z[0][pidx(brev11(n))] = make_float2(va, vb);
        }
        __syncthreads();
        if (tid < 256) octet_pass<1, 0>(z[0], tid);
        __syncthreads();
        if (tid < 256) octet_pass<8, 3>(z[0], tid);
        __syncthreads();
        if (tid < 256) octet_pass<64, 6>(z[0], tid);
        __syncthreads();
        {
            float s, cc;
            __sincosf((float)tid * (-3.14159265358979323846f / 1024.0f), &s, &cc);
            const float2 w2  = make_float2(cc, s);
            const float2 w1  = csqr(w2);
            const float2 w2m = make_float2(w2.y, -w2.x);
            quad_core(z[0], tid, w1, w2, w2m);
        }
        __syncthreads();
#pragma unroll
        for (int it = 0; it < 3; ++it) {
            const int k = tid + it * 512;
            if (k < NBINS) {
                const int km = (N_FFT - k) & (N_FFT - 1);
                const float2 zk = z[0][pidx(k)];
                const float2 zr = z[0][pidx(km)];
                const size_t o = ((size_t)b * NBINS + (size_t)k) * NFRAMES + 512;
                outr[o] = 0.5f * (zk.x + zr.x);
                outi[o] = 0.5f * (zk.y - zr.y);
            }
        }
        return;
    }

    // ---------------- main blocks ----------------
    // XCD swizzle (R9): octets of consecutive g (one 128 B output-line span)
    // get ids differing by 8 (same XCD) in adjacent slots (co-resident).
    const int m    = d - NBATCH;                  // [0,2048)
    const int xcd  = m & 7;
    const int slot = m >> 3;                      // [0,256)
    const int O    = (slot >> 3) * 8 + xcd;       // octet id [0,256)
    const int L    = O * 8 + (slot & 7);          // logical block [0,2048)
    const int b    = L >> 7;
    const int g    = L & 127;
    const int f0   = g * 4;

    const float* xb = x + (size_t)b * TLEN;

    // ---- load 4 windowed frames (2 planes), bit-reversed ----
    if (g >= 1 && g <= 126) {
        // interior: refl() dead (span [1024, 260607]); all 16B-aligned.
#pragma unroll
        for (int it = 0; it < 2; ++it) {
            const int idx = tid + it * 512;       // [0,1024)
            const int c   = idx >> 9;
            const int j   = idx & 511;
            const int n0  = j << 2;
            const int a0  = (f0 + 2 * c) * HOP - PADL;
            const float4 w4 = *reinterpret_cast<const float4*>(&window[n0]);
            const float4 a4 = *reinterpret_cast<const float4*>(&xb[a0 + n0]);
            const float4 b4 = *reinterpret_cast<const float4*>(&xb[a0 + HOP + n0]);
            const int r0 = (int)(__brev((unsigned)j) >> 23);   // brev9(j)
            // brev11(4j+u) = brev9(j) + {0,1024,512,1536}[u]
            z[c][pidx(r0)]        = make_float2(a4.x * w4.x, b4.x * w4.x);
            z[c][pidx(r0 + 1024)] = make_float2(a4.y * w4.y, b4.y * w4.y);
            z[c][pidx(r0 + 512)]  = make_float2(a4.z * w4.z, b4.z * w4.z);
            z[c][pidx(r0 + 1536)] = make_float2(a4.w * w4.w, b4.w * w4.w);
        }
    } else {
        // edge blocks (g==0, g==127): scalar refl path (R9 loader)
#pragma unroll
        for (int it = 0; it < 8; ++it) {
            const int idx = tid + it * 512;       // [0,4096)
            const int c   = idx >> 11;
            const int n   = idx & 2047;
            const int fa  = f0 + 2 * c;
            const float w  = window[n];
            const float va = xb[refl(fa * HOP - PADL + n)] * w;
            const float vb = xb[refl((fa + 1) * HOP - PADL + n)] * w;
            z[c][pidx(brev11(n))] = make_float2(va, vb);
        }
    }
    __syncthreads();

    // ---- stages 1-9: three radix-8 register trips ----
    {
        const int c = tid >> 8, q = tid & 255;
        octet_pass<1, 0>(z[c], q);  __syncthreads();
        octet_pass<8, 3>(z[c], q);  __syncthreads();
        octet_pass<64, 6>(z[c], q); __syncthreads();
    }

    // ---- stages 10-11 in registers; stash v2/v3 for the partner ----
    const int p = tid;                            // [0,512)
    float2 V0[2], V1[2], V2[2], V3[2];
    {
        float s, cc;
        __sincosf((float)p * (-3.14159265358979323846f / 1024.0f), &s, &cc);
        const float2 w2  = make_float2(cc, s);    // exp(-i*pi*p/1024)
        const float2 w1  = csqr(w2);              // exp(-i*pi*p/512)
        const float2 w2m = make_float2(w2.y, -w2.x);
#pragma unroll
        for (int c = 0; c < 2; ++c) {
            float2 v0 = z[c][pidx(p)];
            float2 v1 = z[c][pidx(p + 512)];
            float2 v2 = z[c][pidx(p + 1024)];
            float2 v3 = z[c][pidx(p + 1536)];
            float2 t;
            t = cmul(v1, w1); v1 = csub(v0, t); v0 = cadd(v0, t);
            t = cmul(v3, w1); v3 = csub(v2, t); v2 = cadd(v2, t);
            t = cmul(v2, w2);  v2 = csub(v0, t); v0 = cadd(v0, t);
            t = cmul(v3, w2m); v3 = csub(v1, t); v1 = cadd(v1, t);
            // owner-private slots (same as the thread's own reads): race-free
            z[c][pidx(p + 1024)] = v2;            // X[p+1024]
            z[c][pidx(p + 1536)] = v3;            // X[p+1536]
            V0[c] = v0; V1[c] = v1; V2[c] = v2; V3[c] = v3;
        }
    }
    __syncthreads();

    // ---- fused conjugate-symmetry epilogue: rows k=p and k=p+512 ----
    const size_t row0 = ((size_t)b * NBINS + (size_t)p) * NFRAMES + (size_t)f0;
    const size_t rowS = (size_t)512 * NFRAMES;
    if (p == 0) {
        // k=0: zr = X[0] = v0 ; k=512: zr = X[1536] = own v3 ; k=1024: zk=zr=v2
        store_row(outr + row0, outi + row0, V0[0], V0[0], V0[1], V0[1]);
        store_row(outr + row0 + rowS, outi + row0 + rowS, V1[0], V3[0], V1[1], V3[1]);
        store_row(outr + row0 + 2 * rowS, outi + row0 + 2 * rowS, V2[0], V2[0], V2[1], V2[1]);
    } else {
        // partner thread q=512-p stashed X[2048-p] (its v3) and X[1536-p] (its v2)
        const float2 zr0a = z[0][pidx(2048 - p)];
        const float2 zr1a = z[1][pidx(2048 - p)];
        const float2 zr0b = z[0][pidx(1536 - p)];
        const float2 zr1b = z[1][pidx(1536 - p)];
        store_row(outr + row0, outi + row0, V0[0], zr0a, V0[1], zr1a);
        store_row(outr + row0 + rowS, outi + row0 + rowS, V1[0], zr0b, V1[1], zr1b);
    }
}

extern "C" void kernel_launch(void* const* d_in, const int* in_sizes, int n_in,
                              void* d_out, int out_size, void* d_ws, size_t ws_size,
                              hipStream_t stream) {
    const float* x      = (const float*)d_in[0];
    const float* window = (const float*)d_in[1];
    float* out          = (float*)d_out;

    dim3 grid(2064);   // 16 tail (first) + 2048 main; d_ws deliberately unused
    stft_one<<<grid, 512, 0, stream>>>(x, window, out);
}